// Round 1
// baseline (404.753 us; speedup 1.0000x reference)
//
#include <hip/hip_runtime.h>
#include <math.h>

#define N_NODES 100000
#define E_EDGES 1600000
#define F_IN 32
#define HID 16
#define NC 10

// ---------------- Kernel 1: per-node projections for layer 1 ----------------
// y0 = x @ W1[0], y1 = x @ W1[1], r1 = x @ root1 + b1
__global__ __launch_bounds__(256) void node_l1(
    const float* __restrict__ x, const float* __restrict__ W1,
    const float* __restrict__ root1, const float* __restrict__ b1,
    float* __restrict__ y0, float* __restrict__ y1, float* __restrict__ r1)
{
    __shared__ float sW0[F_IN * HID], sW1[F_IN * HID], sR[F_IN * HID], sB[HID];
    for (int i = threadIdx.x; i < F_IN * HID; i += 256) {
        sW0[i] = W1[i];
        sW1[i] = W1[F_IN * HID + i];
        sR[i]  = root1[i];
    }
    if (threadIdx.x < HID) sB[threadIdx.x] = b1[threadIdx.x];
    __syncthreads();

    int n = blockIdx.x * 256 + threadIdx.x;
    if (n >= N_NODES) return;

    float xr[F_IN];
    const float4* xp = (const float4*)(x + (size_t)n * F_IN);
    #pragma unroll
    for (int i = 0; i < F_IN / 4; i++) {
        float4 t = xp[i];
        xr[i*4+0] = t.x; xr[i*4+1] = t.y; xr[i*4+2] = t.z; xr[i*4+3] = t.w;
    }

    float a0[HID], a1[HID], ar[HID];
    #pragma unroll
    for (int o = 0; o < HID; o++) { a0[o] = 0.f; a1[o] = 0.f; ar[o] = sB[o]; }
    for (int i = 0; i < F_IN; i++) {
        float xi = xr[i];
        #pragma unroll
        for (int o = 0; o < HID; o++) {
            a0[o] += xi * sW0[i * HID + o];
            a1[o] += xi * sW1[i * HID + o];
            ar[o] += xi * sR[i * HID + o];
        }
    }
    float* py0 = y0 + (size_t)n * HID;
    float* py1 = y1 + (size_t)n * HID;
    float* pr  = r1 + (size_t)n * HID;
    #pragma unroll
    for (int o = 0; o < HID; o++) { py0[o] = a0[o]; py1[o] = a1[o]; pr[o] = ar[o]; }
}

// ---------------- Kernel 2: edge gather/scatter for layer 1 ----------------
// 16 lanes per edge; lane o handles output component o.
__global__ __launch_bounds__(256) void edge_l1(
    const int* __restrict__ ei, const float* __restrict__ ea,
    const float* __restrict__ y0, const float* __restrict__ y1,
    float* __restrict__ agg, float* __restrict__ deg)
{
    int idx = blockIdx.x * 256 + threadIdx.x;
    int e = idx >> 4, o = idx & 15;
    if (e >= E_EDGES) return;
    int src = ei[e];
    int dst = ei[E_EDGES + e];
    float v = ea[e];                 // K=2: basis = [1-v, v]
    float m = y0[(size_t)src * HID + o] * (1.0f - v) + y1[(size_t)src * HID + o] * v;
    atomicAdd(&agg[(size_t)dst * HID + o], m);
    if (o == 0) atomicAdd(&deg[dst], 1.0f);
}

// -------- Kernel 3: finish layer 1 (mean + root + elu), prep layer 2 --------
__global__ __launch_bounds__(256) void node_mid(
    const float* __restrict__ agg1, const float* __restrict__ deg,
    const float* __restrict__ r1,
    const float* __restrict__ W2, const float* __restrict__ root2,
    const float* __restrict__ b2,
    float* __restrict__ z0, float* __restrict__ z1, float* __restrict__ r2)
{
    __shared__ float sW0[HID * NC], sW1[HID * NC], sR[HID * NC], sB[NC];
    for (int i = threadIdx.x; i < HID * NC; i += 256) {
        sW0[i] = W2[i];
        sW1[i] = W2[HID * NC + i];
        sR[i]  = root2[i];
    }
    if (threadIdx.x < NC) sB[threadIdx.x] = b2[threadIdx.x];
    __syncthreads();

    int n = blockIdx.x * 256 + threadIdx.x;
    if (n >= N_NODES) return;

    float inv = 1.0f / fmaxf(deg[n], 1.0f);
    float h[HID];
    #pragma unroll
    for (int o = 0; o < HID; o++) {
        float hv = agg1[(size_t)n * HID + o] * inv + r1[(size_t)n * HID + o];
        h[o] = hv > 0.0f ? hv : expm1f(hv);   // elu
    }
    float a0[NC], a1[NC], ar[NC];
    #pragma unroll
    for (int c = 0; c < NC; c++) { a0[c] = 0.f; a1[c] = 0.f; ar[c] = sB[c]; }
    for (int i = 0; i < HID; i++) {
        float hi = h[i];
        #pragma unroll
        for (int c = 0; c < NC; c++) {
            a0[c] += hi * sW0[i * NC + c];
            a1[c] += hi * sW1[i * NC + c];
            ar[c] += hi * sR[i * NC + c];
        }
    }
    float* pz0 = z0 + (size_t)n * NC;
    float* pz1 = z1 + (size_t)n * NC;
    float* pr  = r2 + (size_t)n * NC;
    #pragma unroll
    for (int c = 0; c < NC; c++) { pz0[c] = a0[c]; pz1[c] = a1[c]; pr[c] = ar[c]; }
}

// ---------------- Kernel 4: edge gather/scatter for layer 2 ----------------
__global__ __launch_bounds__(256) void edge_l2(
    const int* __restrict__ ei, const float* __restrict__ ea,
    const float* __restrict__ z0, const float* __restrict__ z1,
    float* __restrict__ agg2)
{
    int idx = blockIdx.x * 256 + threadIdx.x;
    int e = idx >> 4, o = idx & 15;
    if (e >= E_EDGES || o >= NC) return;
    int src = ei[e];
    int dst = ei[E_EDGES + e];
    float v = ea[e];
    float m = z0[(size_t)src * NC + o] * (1.0f - v) + z1[(size_t)src * NC + o] * v;
    atomicAdd(&agg2[(size_t)dst * NC + o], m);
}

// ---------------- Kernel 5: mean + root + log_softmax -> out ----------------
__global__ __launch_bounds__(256) void node_out(
    const float* __restrict__ agg2, const float* __restrict__ deg,
    const float* __restrict__ r2, float* __restrict__ out)
{
    int n = blockIdx.x * 256 + threadIdx.x;
    if (n >= N_NODES) return;
    float inv = 1.0f / fmaxf(deg[n], 1.0f);
    float vv[NC];
    float mx = -1e30f;
    #pragma unroll
    for (int c = 0; c < NC; c++) {
        vv[c] = agg2[(size_t)n * NC + c] * inv + r2[(size_t)n * NC + c];
        mx = fmaxf(mx, vv[c]);
    }
    float s = 0.f;
    #pragma unroll
    for (int c = 0; c < NC; c++) s += expf(vv[c] - mx);
    float ls = logf(s);
    float* po = out + (size_t)n * NC;
    #pragma unroll
    for (int c = 0; c < NC; c++) po[c] = vv[c] - mx - ls;
}

extern "C" void kernel_launch(void* const* d_in, const int* in_sizes, int n_in,
                              void* d_out, int out_size, void* d_ws, size_t ws_size,
                              hipStream_t stream) {
    const float* x     = (const float*)d_in[0];
    const int*   ei    = (const int*)d_in[1];     // [2,E] src row then dst row
    const float* ea    = (const float*)d_in[2];   // [E,1]
    const float* W1    = (const float*)d_in[3];   // [2,32,16]
    const float* root1 = (const float*)d_in[4];   // [32,16]
    const float* b1    = (const float*)d_in[5];   // [16]
    const float* W2    = (const float*)d_in[6];   // [2,16,10]
    const float* root2 = (const float*)d_in[7];   // [16,10]
    const float* b2    = (const float*)d_in[8];   // [10]
    float* out = (float*)d_out;

    // Workspace layout (floats):
    float* ws = (float*)d_ws;
    size_t off = 0;
    float* y0   = ws + off; off += (size_t)N_NODES * HID;
    float* y1   = ws + off; off += (size_t)N_NODES * HID;
    float* r1   = ws + off; off += (size_t)N_NODES * HID;
    float* z0   = ws + off; off += (size_t)N_NODES * NC;
    float* z1   = ws + off; off += (size_t)N_NODES * NC;
    float* r2   = ws + off; off += (size_t)N_NODES * NC;
    // zeroed region: agg1 | deg | agg2 (contiguous, single memset)
    float* agg1 = ws + off; off += (size_t)N_NODES * HID;
    float* deg  = ws + off; off += (size_t)N_NODES;
    float* agg2 = ws + off; off += (size_t)N_NODES * NC;

    size_t zero_bytes = (size_t)N_NODES * (HID + 1 + NC) * sizeof(float);
    hipMemsetAsync(agg1, 0, zero_bytes, stream);

    int nodeGrid = (N_NODES + 255) / 256;
    int edgeGrid = ((E_EDGES * 16) + 255) / 256;

    node_l1<<<nodeGrid, 256, 0, stream>>>(x, W1, root1, b1, y0, y1, r1);
    edge_l1<<<edgeGrid, 256, 0, stream>>>(ei, ea, y0, y1, agg1, deg);
    node_mid<<<nodeGrid, 256, 0, stream>>>(agg1, deg, r1, W2, root2, b2, z0, z1, r2);
    edge_l2<<<edgeGrid, 256, 0, stream>>>(ei, ea, z0, z1, agg2);
    node_out<<<nodeGrid, 256, 0, stream>>>(agg2, deg, r2, out);
}